// Round 1
// baseline (1625.927 us; speedup 1.0000x reference)
//
#include <hip/hip_runtime.h>
#include <math.h>

// Problem constants
#define B_  16
#define LU_ 2048
#define LV_ 2048
#define D_  1024
#define NT_ (LV_ / 128)   // 16 v-tiles of 128

typedef __attribute__((ext_vector_type(8))) short bf16x8;
typedef __attribute__((ext_vector_type(4))) float f32x4;

__device__ __forceinline__ unsigned short f2bf(float x) {
    unsigned int u = __builtin_bit_cast(unsigned int, x);
    u += 0x7fffu + ((u >> 16) & 1u);          // RNE
    return (unsigned short)(u >> 16);
}
__device__ __forceinline__ float bf2f(unsigned short h) {
    unsigned int u = ((unsigned int)h) << 16;
    return __builtin_bit_cast(float, u);
}

__device__ __forceinline__ void gload_lds16(const void* g, void* l) {
    __builtin_amdgcn_global_load_lds(
        (const __attribute__((address_space(1))) void*)g,
        (__attribute__((address_space(3))) void*)l, 16, 0, 0);
}

// split 16 fp32 -> hi/lo bf16, write 2x16B each to LDS
__device__ __forceinline__ void store_split16(float4 a, float4 b, float4 c, float4 d,
                                              unsigned short* hi, unsigned short* lo) {
    float x[16] = {a.x,a.y,a.z,a.w, b.x,b.y,b.z,b.w, c.x,c.y,c.z,c.w, d.x,d.y,d.z,d.w};
    bf16x8 h0, h1, l0, l1;
#pragma unroll
    for (int j = 0; j < 8; j++) {
        unsigned short hh = f2bf(x[j]);
        h0[j] = (short)hh;
        l0[j] = (short)f2bf(x[j] - bf2f(hh));
    }
#pragma unroll
    for (int j = 0; j < 8; j++) {
        unsigned short hh = f2bf(x[8 + j]);
        h1[j] = (short)hh;
        l1[j] = (short)f2bf(x[8 + j] - bf2f(hh));
    }
    ((bf16x8*)hi)[0] = h0;  ((bf16x8*)hi)[1] = h1;
    ((bf16x8*)lo)[0] = l0;  ((bf16x8*)lo)[1] = l1;
}

// ---------------------------------------------------------------------------
// K0: per-batch valid length from mask, with byte-vs-int32 layout detection.
// mask is monotone per row (False^L True^(LV-L)), L >= LV/2.
__global__ void lengths_kernel(const void* __restrict__ mask, int* __restrict__ lengths) {
    __shared__ int viol;
    __shared__ int cnt[B_];
    const int t = threadIdx.x;
    if (t == 0) viol = 0;
    if (t < B_) cnt[t] = 0;
    __syncthreads();
    const unsigned char* mb = (const unsigned char*)mask;
    int local = 0;
    // uint8 interpretation must be monotone within each LV-byte row.
    for (int i = t; i < B_ * LV_ - 1; i += 256) {
        if (((i + 1) % LV_) != 0) {
            if (mb[i] != 0 && mb[i + 1] == 0) local++;
        }
    }
    if (local) atomicAdd(&viol, local);
    __syncthreads();
    const bool is_i32 = (viol > 0);
    const int b = t >> 4, s = t & 15;
    int c = 0;
    if (is_i32) {
        const int* mi = (const int*)mask;
        for (int v2 = s; v2 < LV_; v2 += 16) c += (mi[b * LV_ + v2] == 0) ? 1 : 0;
    } else {
        for (int v2 = s; v2 < LV_; v2 += 16) c += (mb[b * LV_ + v2] == 0) ? 1 : 0;
    }
    atomicAdd(&cnt[b], c);
    __syncthreads();
    if (t < B_) lengths[t] = cnt[t];
}

// ---------------------------------------------------------------------------
// K1: Y = relu(X @ W^T + bias), stored as bf16 hi/lo. M=grid.x*128, N=K=1024.
// 128x128 tile, BK=32 fp32, 4 waves (2x2 of 64x64), 3-term hi/lo MFMA.
__global__ __launch_bounds__(256, 2) void proj_kernel(
    const float* __restrict__ X, const float* __restrict__ W,
    const float* __restrict__ bias,
    unsigned short* __restrict__ Yhi, unsigned short* __restrict__ Ylo) {
    const int K = D_, N = D_;
    __shared__ alignas(16) unsigned short Ah[128 * 40], Al[128 * 40],
                                          Bh[128 * 40], Bl[128 * 40];
    const int t = threadIdx.x;
    const int lane = t & 63, w = t >> 6;
    const int wr = (w >> 1) * 64, wc = (w & 1) * 64;
    const int fr = lane & 15, fg = lane >> 4, fk = fg * 8;
    const int row0 = blockIdx.x * 128, col0 = blockIdx.y * 128;

    const f32x4 fzero = {0.f, 0.f, 0.f, 0.f};
    f32x4 acc[4][4];
#pragma unroll
    for (int m = 0; m < 4; m++)
#pragma unroll
        for (int n = 0; n < 4; n++) acc[m][n] = fzero;

    const int sr = t >> 1;           // 0..127
    const int sh = (t & 1) * 16;     // k sub-offset 0/16
    const float* Xp = X + (size_t)(row0 + sr) * K + sh;
    const float* Wp = W + (size_t)(col0 + sr) * K + sh;
    unsigned short* ahp = &Ah[sr * 40 + sh];
    unsigned short* alp = &Al[sr * 40 + sh];
    unsigned short* bhp = &Bh[sr * 40 + sh];
    unsigned short* blp = &Bl[sr * 40 + sh];

    for (int k0 = 0; k0 < K; k0 += 32) {
        float4 xv0 = ((const float4*)(Xp + k0))[0];
        float4 xv1 = ((const float4*)(Xp + k0))[1];
        float4 xv2 = ((const float4*)(Xp + k0))[2];
        float4 xv3 = ((const float4*)(Xp + k0))[3];
        float4 wv0 = ((const float4*)(Wp + k0))[0];
        float4 wv1 = ((const float4*)(Wp + k0))[1];
        float4 wv2 = ((const float4*)(Wp + k0))[2];
        float4 wv3 = ((const float4*)(Wp + k0))[3];
        __syncthreads();
        store_split16(xv0, xv1, xv2, xv3, ahp, alp);
        store_split16(wv0, wv1, wv2, wv3, bhp, blp);
        __syncthreads();

        bf16x8 fah[4], fal[4], fbh[4], fbl[4];
#pragma unroll
        for (int m = 0; m < 4; m++) {
            fah[m] = *(const bf16x8*)&Ah[(wr + m * 16 + fr) * 40 + fk];
            fal[m] = *(const bf16x8*)&Al[(wr + m * 16 + fr) * 40 + fk];
        }
#pragma unroll
        for (int n = 0; n < 4; n++) {
            fbh[n] = *(const bf16x8*)&Bh[(wc + n * 16 + fr) * 40 + fk];
            fbl[n] = *(const bf16x8*)&Bl[(wc + n * 16 + fr) * 40 + fk];
        }
#pragma unroll
        for (int m = 0; m < 4; m++)
#pragma unroll
            for (int n = 0; n < 4; n++) {
                acc[m][n] = __builtin_amdgcn_mfma_f32_16x16x32_bf16(fah[m], fbh[n], acc[m][n], 0, 0, 0);
                acc[m][n] = __builtin_amdgcn_mfma_f32_16x16x32_bf16(fah[m], fbl[n], acc[m][n], 0, 0, 0);
                acc[m][n] = __builtin_amdgcn_mfma_f32_16x16x32_bf16(fal[m], fbh[n], acc[m][n], 0, 0, 0);
            }
    }

#pragma unroll
    for (int n = 0; n < 4; n++) {
        const int col = col0 + wc + n * 16 + fr;
        const float bv = bias[col];
#pragma unroll
        for (int m = 0; m < 4; m++) {
            const int rbase = row0 + wr + m * 16 + fg * 4;
#pragma unroll
            for (int j = 0; j < 4; j++) {
                float y = acc[m][n][j] + bv;
                y = fmaxf(y, 0.0f);
                const unsigned short hh = f2bf(y);
                const size_t idx = (size_t)(rbase + j) * N + col;
                Yhi[idx] = hh;
                Ylo[idx] = f2bf(y - bf2f(hh));
            }
        }
    }
}

// ---------------------------------------------------------------------------
// K2: v fp32 [B][LV][D] -> vT bf16 [B][D][LV]
__global__ __launch_bounds__(256) void transpose_v_kernel(
    const float* __restrict__ V, unsigned short* __restrict__ VT) {
    __shared__ unsigned short s[64 * 72];
    const int b = blockIdx.z;
    const int v0 = blockIdx.x * 64, d0 = blockIdx.y * 64;
    const int t = threadIdx.x;
    {
        const int r = t >> 2, q = (t & 3) * 16;
        const float* src = V + ((size_t)b * LV_ + v0 + r) * D_ + d0 + q;
#pragma unroll
        for (int i = 0; i < 4; i++) {
            float4 x = ((const float4*)src)[i];
            s[r * 72 + q + i * 4 + 0] = f2bf(x.x);
            s[r * 72 + q + i * 4 + 1] = f2bf(x.y);
            s[r * 72 + q + i * 4 + 2] = f2bf(x.z);
            s[r * 72 + q + i * 4 + 3] = f2bf(x.w);
        }
    }
    __syncthreads();
    {
        const int d = t >> 2, vq = (t & 3) * 16;
        bf16x8 t0, t1;
#pragma unroll
        for (int j = 0; j < 8; j++) t0[j] = (short)s[(vq + j) * 72 + d];
#pragma unroll
        for (int j = 0; j < 8; j++) t1[j] = (short)s[(vq + 8 + j) * 72 + d];
        unsigned short* dst = VT + ((size_t)b * D_ + d0 + d) * LV_ + v0 + vq;
        ((bf16x8*)dst)[0] = t0;
        ((bf16x8*)dst)[1] = t1;
    }
}

// ---------------------------------------------------------------------------
// K3: flash-style logits. WG = (b, 64 u-rows), 4 waves of 16 rows x 128 cols.
// 3-term hi/lo MFMA logits; online (m,Z) wave-local; write P'=exp(S-m_run) bf16.
__global__ __launch_bounds__(256, 2) void attn_logits_kernel(
    const unsigned short* __restrict__ Uh, const unsigned short* __restrict__ Ul,
    const unsigned short* __restrict__ Vh, const unsigned short* __restrict__ Vl,
    const int* __restrict__ lengths,
    unsigned short* __restrict__ Pp, float* __restrict__ m_used,
    float* __restrict__ m_fin, float* __restrict__ Zf) {
    __shared__ alignas(16) unsigned short sUh[64 * 40], sUl[64 * 40],
                                          sVh[128 * 40], sVl[128 * 40];
    const int b = blockIdx.y, ut = blockIdx.x;
    const int t = threadIdx.x, lane = t & 63, w = t >> 6;
    const int fr = lane & 15, fg = lane >> 4, fk = fg * 8;
    const int length = lengths[b];
    const size_t ubase = ((size_t)b * LU_ + ut * 64) * D_;
    const size_t vbase = (size_t)b * LV_ * D_;
    const int urow = t >> 2, uq = (t & 3) * 8;   // U stage: 64 rows x 32 shorts
    const int vrow = t >> 1, vq = (t & 1) * 16;  // V stage: 128 rows x 32 shorts

    float m_run[4], Z_run[4];
#pragma unroll
    for (int j = 0; j < 4; j++) { m_run[j] = -__builtin_inff(); Z_run[j] = 0.f; }

    const f32x4 fzero = {0.f, 0.f, 0.f, 0.f};

    for (int vt = 0; vt < NT_; ++vt) {
        f32x4 acc[8];
#pragma unroll
        for (int n = 0; n < 8; n++) acc[n] = fzero;
        const size_t vtb = vbase + (size_t)(vt * 128) * D_;

        for (int k0 = 0; k0 < D_; k0 += 32) {
            const bf16x8 uh = *(const bf16x8*)&Uh[ubase + (size_t)urow * D_ + k0 + uq];
            const bf16x8 ul = *(const bf16x8*)&Ul[ubase + (size_t)urow * D_ + k0 + uq];
            const bf16x8 vh0 = *(const bf16x8*)&Vh[vtb + (size_t)vrow * D_ + k0 + vq];
            const bf16x8 vh1 = *(const bf16x8*)&Vh[vtb + (size_t)vrow * D_ + k0 + vq + 8];
            const bf16x8 vl0 = *(const bf16x8*)&Vl[vtb + (size_t)vrow * D_ + k0 + vq];
            const bf16x8 vl1 = *(const bf16x8*)&Vl[vtb + (size_t)vrow * D_ + k0 + vq + 8];
            __syncthreads();
            *(bf16x8*)&sUh[urow * 40 + uq] = uh;
            *(bf16x8*)&sUl[urow * 40 + uq] = ul;
            *(bf16x8*)&sVh[vrow * 40 + vq] = vh0;
            *(bf16x8*)&sVh[vrow * 40 + vq + 8] = vh1;
            *(bf16x8*)&sVl[vrow * 40 + vq] = vl0;
            *(bf16x8*)&sVl[vrow * 40 + vq + 8] = vl1;
            __syncthreads();

            const bf16x8 ah = *(const bf16x8*)&sUh[(w * 16 + fr) * 40 + fk];
            const bf16x8 al = *(const bf16x8*)&sUl[(w * 16 + fr) * 40 + fk];
#pragma unroll
            for (int n = 0; n < 8; n++) {
                const bf16x8 bh = *(const bf16x8*)&sVh[(n * 16 + fr) * 40 + fk];
                const bf16x8 bl = *(const bf16x8*)&sVl[(n * 16 + fr) * 40 + fk];
                acc[n] = __builtin_amdgcn_mfma_f32_16x16x32_bf16(ah, bh, acc[n], 0, 0, 0);
                acc[n] = __builtin_amdgcn_mfma_f32_16x16x32_bf16(ah, bl, acc[n], 0, 0, 0);
                acc[n] = __builtin_amdgcn_mfma_f32_16x16x32_bf16(al, bh, acc[n], 0, 0, 0);
            }
        }

        // --- online softmax stats for this v-tile (wave-local rows) ---
        float mt[4] = {-__builtin_inff(), -__builtin_inff(), -__builtin_inff(), -__builtin_inff()};
#pragma unroll
        for (int n = 0; n < 8; n++) {
            const int col = vt * 128 + n * 16 + fr;
            if (col < length) {
#pragma unroll
                for (int j = 0; j < 4; j++) mt[j] = fmaxf(mt[j], acc[n][j]);
            }
        }
#pragma unroll
        for (int d = 1; d < 16; d <<= 1) {
#pragma unroll
            for (int j = 0; j < 4; j++) mt[j] = fmaxf(mt[j], __shfl_xor(mt[j], d));
        }
#pragma unroll
        for (int j = 0; j < 4; j++) {
            const float mn = fmaxf(m_run[j], mt[j]);
            Z_run[j] *= __expf(m_run[j] - mn);   // 0*0 on first tile -> 0, no NaN
            m_run[j] = mn;
        }
        float rs[4] = {0.f, 0.f, 0.f, 0.f};
#pragma unroll
        for (int n = 0; n < 8; n++) {
            const int col = vt * 128 + n * 16 + fr;
            const bool valid = (col < length);
#pragma unroll
            for (int j = 0; j < 4; j++) {
                const float p = valid ? __expf(acc[n][j] - m_run[j]) : 0.f;
                rs[j] += p;
                const size_t row = (size_t)b * LU_ + ut * 64 + w * 16 + fg * 4 + j;
                Pp[row * LV_ + col] = f2bf(p);
            }
        }
#pragma unroll
        for (int d = 1; d < 16; d <<= 1) {
#pragma unroll
            for (int j = 0; j < 4; j++) rs[j] += __shfl_xor(rs[j], d);
        }
#pragma unroll
        for (int j = 0; j < 4; j++) Z_run[j] += rs[j];
        if (fr == 0) {
#pragma unroll
            for (int j = 0; j < 4; j++) {
                const size_t row = (size_t)b * LU_ + ut * 64 + w * 16 + fg * 4 + j;
                m_used[row * NT_ + vt] = m_run[j];
            }
        }
    }
    if (fr == 0) {
#pragma unroll
        for (int j = 0; j < 4; j++) {
            const size_t row = (size_t)b * LU_ + ut * 64 + w * 16 + fg * 4 + j;
            m_fin[row] = m_run[j];
            Zf[row] = Z_run[j];
        }
    }
}

// ---------------------------------------------------------------------------
// K4: P = P' * exp(m_used - m_fin) / Z  (in place, bf16)
__global__ __launch_bounds__(256) void rescale_kernel(
    unsigned short* __restrict__ Pp, const float* __restrict__ m_used,
    const float* __restrict__ m_fin, const float* __restrict__ Zf) {
    const size_t i = (size_t)blockIdx.x * 256 + threadIdx.x;
    const size_t e = i * 8;
    const size_t row = e >> 11;             // / LV_
    const int vv = (int)(e & (LV_ - 1));
    const int tile = vv >> 7;
    const float sc = __expf(m_used[row * NT_ + tile] - m_fin[row]) / Zf[row];
    bf16x8 x = *(bf16x8*)&Pp[e];
    bf16x8 o;
#pragma unroll
    for (int j = 0; j < 8; j++)
        o[j] = (short)f2bf(bf2f((unsigned short)x[j]) * sc);
    *(bf16x8*)&Pp[e] = o;
}

// ---------------------------------------------------------------------------
// K5: out[b] = P[b] @ v[b]  (A = P bf16 [LU][LV], B = vT bf16 [D][LV], both K-major)
// m97-style 128x128 tile, BK=64, global_load_lds width 16, fp32 out.
__global__ __launch_bounds__(256, 2) void pv_gemm_kernel(
    const unsigned short* __restrict__ P, const unsigned short* __restrict__ VT,
    float* __restrict__ Out) {
    __shared__ alignas(16) unsigned short sA[128 * 64], sB[128 * 64];
    const int b = blockIdx.z, bm = blockIdx.x, bn = blockIdx.y;
    const int t = threadIdx.x, lane = t & 63, w = t >> 6;
    const int wr = (w >> 1) * 64, wc = (w & 1) * 64;
    const int fr = lane & 15, fg = lane >> 4, fk = fg * 8;
    const unsigned short* Ab = P + (size_t)b * LU_ * LV_ + (size_t)bm * 128 * LV_;
    const unsigned short* Bb = VT + (size_t)b * D_ * LV_ + (size_t)bn * 128 * LV_;

    const f32x4 fzero = {0.f, 0.f, 0.f, 0.f};
    f32x4 acc[4][4];
#pragma unroll
    for (int m = 0; m < 4; m++)
#pragma unroll
        for (int n = 0; n < 4; n++) acc[m][n] = fzero;

    for (int k0 = 0; k0 < LV_; k0 += 64) {
        __syncthreads();
#pragma unroll
        for (int i = 0; i < 4; i++) {
            const int id = i * 256 + t;
            const int r = id >> 3;
            const int c = (id & 7) * 8;
            gload_lds16(Ab + (size_t)r * LV_ + k0 + c, &sA[(i * 256 + w * 64) * 8]);
            gload_lds16(Bb + (size_t)r * LV_ + k0 + c, &sB[(i * 256 + w * 64) * 8]);
        }
        __syncthreads();
#pragma unroll
        for (int kk = 0; kk < 2; kk++) {
            bf16x8 af[4], bfr[4];
#pragma unroll
            for (int m = 0; m < 4; m++)
                af[m] = *(const bf16x8*)&sA[(wr + m * 16 + fr) * 64 + kk * 32 + fk];
#pragma unroll
            for (int n = 0; n < 4; n++)
                bfr[n] = *(const bf16x8*)&sB[(wc + n * 16 + fr) * 64 + kk * 32 + fk];
#pragma unroll
            for (int m = 0; m < 4; m++)
#pragma unroll
                for (int n = 0; n < 4; n++)
                    acc[m][n] = __builtin_amdgcn_mfma_f32_16x16x32_bf16(af[m], bfr[n], acc[m][n], 0, 0, 0);
        }
    }

    float* Ob = Out + (size_t)b * LU_ * D_;
#pragma unroll
    for (int m = 0; m < 4; m++) {
        const int rbase = bm * 128 + wr + m * 16 + fg * 4;
#pragma unroll
        for (int n = 0; n < 4; n++) {
            const int col = bn * 128 + wc + n * 16 + fr;
#pragma unroll
            for (int j = 0; j < 4; j++)
                Ob[(size_t)(rbase + j) * D_ + col] = acc[m][n][j];
        }
    }
}

// ---------------------------------------------------------------------------
extern "C" void kernel_launch(void* const* d_in, const int* in_sizes, int n_in,
                              void* d_out, int out_size, void* d_ws, size_t ws_size,
                              hipStream_t stream) {
    (void)in_sizes; (void)n_in; (void)out_size; (void)ws_size;
    const float* u    = (const float*)d_in[0];
    const float* v    = (const float*)d_in[1];
    const void*  vm   = d_in[2];
    const float* W    = (const float*)d_in[3];
    const float* bias = (const float*)d_in[4];
    float* out = (float*)d_out;
    char* ws = (char*)d_ws;

    // ws layout (requires ~472 MB)
    unsigned short* u_hi = (unsigned short*)(ws);                 //  64 MiB
    unsigned short* u_lo = (unsigned short*)(ws + 67108864ull);
    unsigned short* v_hi = (unsigned short*)(ws + 134217728ull);
    unsigned short* v_lo = (unsigned short*)(ws + 201326592ull);
    unsigned short* vT   = (unsigned short*)(ws + 268435456ull);
    unsigned short* Pp   = (unsigned short*)(ws + 335544320ull);  // 128 MiB
    float* m_used = (float*)(ws + 469762048ull);                  //   2 MiB
    float* m_fin  = (float*)(ws + 471859200ull);
    float* Zf     = (float*)(ws + 471990272ull);
    int*   lengths = (int*)(ws + 472121344ull);

    lengths_kernel<<<1, 256, 0, stream>>>(vm, lengths);
    proj_kernel<<<dim3(32768 / 128, D_ / 128), 256, 0, stream>>>(u, W, bias, u_hi, u_lo);
    proj_kernel<<<dim3(32768 / 128, D_ / 128), 256, 0, stream>>>(v, W, bias, v_hi, v_lo);
    transpose_v_kernel<<<dim3(LV_ / 64, D_ / 64, B_), 256, 0, stream>>>(v, vT);
    attn_logits_kernel<<<dim3(LU_ / 64, B_), 256, 0, stream>>>(
        u_hi, u_lo, v_hi, v_lo, lengths, Pp, m_used, m_fin, Zf);
    rescale_kernel<<<(B_ * LU_ * LV_ / 8) / 256, 256, 0, stream>>>(Pp, m_used, m_fin, Zf);
    pv_gemm_kernel<<<dim3(LU_ / 128, D_ / 128, B_), 256, 0, stream>>>(Pp, vT, out);
}

// Round 2
// 1201.839 us; speedup vs baseline: 1.3529x; 1.3529x over previous
//
#include <hip/hip_runtime.h>
#include <math.h>

// Problem constants
#define B_  16
#define LU_ 2048
#define LV_ 2048
#define D_  1024
#define NT_ (LV_ / 128)   // 16 v-tiles of 128
#define MB_ (1024ull * 1024ull)

typedef __attribute__((ext_vector_type(8))) short bf16x8;
typedef __attribute__((ext_vector_type(4))) float f32x4;

__device__ __forceinline__ unsigned short f2bf(float x) {
    unsigned int u = __builtin_bit_cast(unsigned int, x);
    u += 0x7fffu + ((u >> 16) & 1u);          // RNE
    return (unsigned short)(u >> 16);
}
__device__ __forceinline__ float bf2f(unsigned short h) {
    unsigned int u = ((unsigned int)h) << 16;
    return __builtin_bit_cast(float, u);
}

__device__ __forceinline__ void gload_lds16(const void* g, void* l) {
    __builtin_amdgcn_global_load_lds(
        (const __attribute__((address_space(1))) void*)g,
        (__attribute__((address_space(3))) void*)l, 16, 0, 0);
}

// ---------------------------------------------------------------------------
// K0: per-batch valid length from mask, with byte-vs-int32 layout detection.
__global__ void lengths_kernel(const void* __restrict__ mask, int* __restrict__ lengths) {
    __shared__ int viol;
    __shared__ int cnt[B_];
    const int t = threadIdx.x;
    if (t == 0) viol = 0;
    if (t < B_) cnt[t] = 0;
    __syncthreads();
    const unsigned char* mb = (const unsigned char*)mask;
    int local = 0;
    for (int i = t; i < B_ * LV_ - 1; i += 256) {
        if (((i + 1) % LV_) != 0) {
            if (mb[i] != 0 && mb[i + 1] == 0) local++;
        }
    }
    if (local) atomicAdd(&viol, local);
    __syncthreads();
    const bool is_i32 = (viol > 0);
    const int b = t >> 4, s = t & 15;
    int c = 0;
    if (is_i32) {
        const int* mi = (const int*)mask;
        for (int v2 = s; v2 < LV_; v2 += 16) c += (mi[b * LV_ + v2] == 0) ? 1 : 0;
    } else {
        for (int v2 = s; v2 < LV_; v2 += 16) c += (mb[b * LV_ + v2] == 0) ? 1 : 0;
    }
    atomicAdd(&cnt[b], c);
    __syncthreads();
    if (t < B_) lengths[t] = cnt[t];
}

// ---------------------------------------------------------------------------
// K1: fp32 -> bf16 hi/lo split (elementwise, 8 elems/thread, grid-stride)
__global__ __launch_bounds__(256) void split_kernel(
    const float* __restrict__ X, unsigned short* __restrict__ hi,
    unsigned short* __restrict__ lo, long n8) {
    const long stride = (long)gridDim.x * 256;
    for (long i = (long)blockIdx.x * 256 + threadIdx.x; i < n8; i += stride) {
        float4 x0 = ((const float4*)X)[i * 2];
        float4 x1 = ((const float4*)X)[i * 2 + 1];
        float xv[8] = {x0.x, x0.y, x0.z, x0.w, x1.x, x1.y, x1.z, x1.w};
        bf16x8 h, l;
#pragma unroll
        for (int j = 0; j < 8; j++) {
            unsigned short hh = f2bf(xv[j]);
            h[j] = (short)hh;
            l[j] = (short)f2bf(xv[j] - bf2f(hh));
        }
        ((bf16x8*)hi)[i] = h;
        ((bf16x8*)lo)[i] = l;
    }
}

// ---------------------------------------------------------------------------
// K2: Y = relu(X @ W^T + b) as bf16 hi/lo. Pure-bf16 3-term MFMA GEMM.
// 128x128 tile, BK=32, 4 waves of 32 rows x 128 cols, gload_lds + swizzle.
__global__ __launch_bounds__(256, 2) void proj_kernel(
    const unsigned short* __restrict__ Xh, const unsigned short* __restrict__ Xl,
    const unsigned short* __restrict__ Wh, const unsigned short* __restrict__ Wl,
    const float* __restrict__ bias,
    unsigned short* __restrict__ Yhi, unsigned short* __restrict__ Ylo) {
    __shared__ alignas(16) unsigned short sAh[128 * 32], sAl[128 * 32],
                                          sBh[128 * 32], sBl[128 * 32];
    const int t = threadIdx.x, lane = t & 63, w = t >> 6;
    const int fr = lane & 15, fg = lane >> 4;
    const int row0 = blockIdx.x * 128, col0 = blockIdx.y * 128;

    // staging geometry: per wave, issue i in {0,1} covers rows [i*64+w*16, +16)
    const int sr0 = w * 16 + (lane >> 2);
    const int sr1 = 64 + sr0;
    const int c0 = (lane & 3) ^ ((sr0 >> 1) & 3);
    const int c1 = (lane & 3) ^ ((sr1 >> 1) & 3);
    const size_t ao0 = (size_t)(row0 + sr0) * D_ + c0 * 8;
    const size_t ao1 = (size_t)(row0 + sr1) * D_ + c1 * 8;
    const size_t bo0 = (size_t)(col0 + sr0) * D_ + c0 * 8;
    const size_t bo1 = (size_t)(col0 + sr1) * D_ + c1 * 8;
    const int db0 = (w * 16) * 32;
    const int db1 = (64 + w * 16) * 32;

    // fragment read offsets (swizzled), loop-invariant
    int aoff[2], boff[8];
#pragma unroll
    for (int m = 0; m < 2; m++) {
        const int r = w * 32 + m * 16 + fr;
        aoff[m] = r * 32 + (fg ^ ((r >> 1) & 3)) * 8;
    }
#pragma unroll
    for (int n = 0; n < 8; n++) {
        const int r = n * 16 + fr;
        boff[n] = r * 32 + (fg ^ ((r >> 1) & 3)) * 8;
    }

    const f32x4 fzero = {0.f, 0.f, 0.f, 0.f};
    f32x4 acc[2][8];
#pragma unroll
    for (int m = 0; m < 2; m++)
#pragma unroll
        for (int n = 0; n < 8; n++) acc[m][n] = fzero;

    for (int k0 = 0; k0 < D_; k0 += 32) {
        __syncthreads();
        gload_lds16(Xh + ao0 + k0, &sAh[db0]);
        gload_lds16(Xh + ao1 + k0, &sAh[db1]);
        gload_lds16(Xl + ao0 + k0, &sAl[db0]);
        gload_lds16(Xl + ao1 + k0, &sAl[db1]);
        gload_lds16(Wh + bo0 + k0, &sBh[db0]);
        gload_lds16(Wh + bo1 + k0, &sBh[db1]);
        gload_lds16(Wl + bo0 + k0, &sBl[db0]);
        gload_lds16(Wl + bo1 + k0, &sBl[db1]);
        __syncthreads();
        const bf16x8 ah0 = *(const bf16x8*)&sAh[aoff[0]];
        const bf16x8 ah1 = *(const bf16x8*)&sAh[aoff[1]];
        const bf16x8 al0 = *(const bf16x8*)&sAl[aoff[0]];
        const bf16x8 al1 = *(const bf16x8*)&sAl[aoff[1]];
#pragma unroll
        for (int n = 0; n < 8; n++) {
            const bf16x8 bh = *(const bf16x8*)&sBh[boff[n]];
            const bf16x8 bl = *(const bf16x8*)&sBl[boff[n]];
            acc[0][n] = __builtin_amdgcn_mfma_f32_16x16x32_bf16(ah0, bh, acc[0][n], 0, 0, 0);
            acc[0][n] = __builtin_amdgcn_mfma_f32_16x16x32_bf16(ah0, bl, acc[0][n], 0, 0, 0);
            acc[0][n] = __builtin_amdgcn_mfma_f32_16x16x32_bf16(al0, bh, acc[0][n], 0, 0, 0);
            acc[1][n] = __builtin_amdgcn_mfma_f32_16x16x32_bf16(ah1, bh, acc[1][n], 0, 0, 0);
            acc[1][n] = __builtin_amdgcn_mfma_f32_16x16x32_bf16(ah1, bl, acc[1][n], 0, 0, 0);
            acc[1][n] = __builtin_amdgcn_mfma_f32_16x16x32_bf16(al1, bh, acc[1][n], 0, 0, 0);
        }
    }

#pragma unroll
    for (int m = 0; m < 2; m++)
#pragma unroll
        for (int n = 0; n < 8; n++) {
            const int col = col0 + n * 16 + fr;
            const float bv = bias[col];
#pragma unroll
            for (int j = 0; j < 4; j++) {
                const int row = row0 + w * 32 + m * 16 + fg * 4 + j;
                float y = fmaxf(acc[m][n][j] + bv, 0.f);
                const unsigned short hh = f2bf(y);
                const size_t idx = (size_t)row * D_ + col;
                Yhi[idx] = hh;
                Ylo[idx] = f2bf(y - bf2f(hh));
            }
        }
}

// ---------------------------------------------------------------------------
// K3: v fp32 [B][LV][D] -> vT bf16 [B][D][LV]
__global__ __launch_bounds__(256) void transpose_v_kernel(
    const float* __restrict__ V, unsigned short* __restrict__ VT) {
    __shared__ unsigned short s[64 * 72];
    const int b = blockIdx.z;
    const int v0 = blockIdx.x * 64, d0 = blockIdx.y * 64;
    const int t = threadIdx.x;
    {
        const int r = t >> 2, q = (t & 3) * 16;
        const float* src = V + ((size_t)b * LV_ + v0 + r) * D_ + d0 + q;
#pragma unroll
        for (int i = 0; i < 4; i++) {
            float4 x = ((const float4*)src)[i];
            s[r * 72 + q + i * 4 + 0] = f2bf(x.x);
            s[r * 72 + q + i * 4 + 1] = f2bf(x.y);
            s[r * 72 + q + i * 4 + 2] = f2bf(x.z);
            s[r * 72 + q + i * 4 + 3] = f2bf(x.w);
        }
    }
    __syncthreads();
    {
        const int d = t >> 2, vq = (t & 3) * 16;
        bf16x8 t0, t1;
#pragma unroll
        for (int j = 0; j < 8; j++) t0[j] = (short)s[(vq + j) * 72 + d];
#pragma unroll
        for (int j = 0; j < 8; j++) t1[j] = (short)s[(vq + 8 + j) * 72 + d];
        unsigned short* dst = VT + ((size_t)b * D_ + d0 + d) * LV_ + v0 + vq;
        ((bf16x8*)dst)[0] = t0;
        ((bf16x8*)dst)[1] = t1;
    }
}

// ---------------------------------------------------------------------------
// K4: logits tile kernel. Grid (LU/128, NT, B). Each WG: one 128x128 S-tile,
// per-tile-local softmax stats, writes P'=exp(S-m_t) bf16 + (m_t, Z_t).
__global__ __launch_bounds__(256, 2) void attn_logits_kernel(
    const unsigned short* __restrict__ Uh, const unsigned short* __restrict__ Ul,
    const unsigned short* __restrict__ Vh, const unsigned short* __restrict__ Vl,
    const int* __restrict__ lengths,
    unsigned short* __restrict__ Pp, float* __restrict__ m_used,
    float* __restrict__ Z_used) {
    __shared__ alignas(16) unsigned short sUh[128 * 32], sUl[128 * 32],
                                          sVh[128 * 32], sVl[128 * 32];
    const int b = blockIdx.z, ut = blockIdx.x, vt = blockIdx.y;
    const int t = threadIdx.x, lane = t & 63, w = t >> 6;
    const int fr = lane & 15, fg = lane >> 4;
    const int length = lengths[b];
    const int row0 = ut * 128, col0 = vt * 128;

    if (col0 >= length) {   // fully-masked tile: zero P', write degenerate stats
        const bf16x8 zv = {0, 0, 0, 0, 0, 0, 0, 0};
        for (int i = t; i < 128 * 16; i += 256) {
            const int r = i >> 4, c = (i & 15) * 8;
            *(bf16x8*)&Pp[(size_t)(b * LU_ + row0 + r) * LV_ + col0 + c] = zv;
        }
        if (t < 128) {
            const size_t row = (size_t)b * LU_ + row0 + t;
            m_used[row * NT_ + vt] = -__builtin_inff();
            Z_used[row * NT_ + vt] = 0.f;
        }
        return;
    }

    const int sr0 = w * 16 + (lane >> 2);
    const int sr1 = 64 + sr0;
    const int c0 = (lane & 3) ^ ((sr0 >> 1) & 3);
    const int c1 = (lane & 3) ^ ((sr1 >> 1) & 3);
    const size_t uo0 = ((size_t)b * LU_ + row0 + sr0) * D_ + c0 * 8;
    const size_t uo1 = ((size_t)b * LU_ + row0 + sr1) * D_ + c1 * 8;
    const size_t vo0 = ((size_t)b * LV_ + col0 + sr0) * D_ + c0 * 8;
    const size_t vo1 = ((size_t)b * LV_ + col0 + sr1) * D_ + c1 * 8;
    const int db0 = (w * 16) * 32;
    const int db1 = (64 + w * 16) * 32;

    int aoff[2], boff[8];
#pragma unroll
    for (int m = 0; m < 2; m++) {
        const int r = w * 32 + m * 16 + fr;
        aoff[m] = r * 32 + (fg ^ ((r >> 1) & 3)) * 8;
    }
#pragma unroll
    for (int n = 0; n < 8; n++) {
        const int r = n * 16 + fr;
        boff[n] = r * 32 + (fg ^ ((r >> 1) & 3)) * 8;
    }

    const f32x4 fzero = {0.f, 0.f, 0.f, 0.f};
    f32x4 acc[2][8];
#pragma unroll
    for (int m = 0; m < 2; m++)
#pragma unroll
        for (int n = 0; n < 8; n++) acc[m][n] = fzero;

    for (int k0 = 0; k0 < D_; k0 += 32) {
        __syncthreads();
        gload_lds16(Uh + uo0 + k0, &sUh[db0]);
        gload_lds16(Uh + uo1 + k0, &sUh[db1]);
        gload_lds16(Ul + uo0 + k0, &sUl[db0]);
        gload_lds16(Ul + uo1 + k0, &sUl[db1]);
        gload_lds16(Vh + vo0 + k0, &sVh[db0]);
        gload_lds16(Vh + vo1 + k0, &sVh[db1]);
        gload_lds16(Vl + vo0 + k0, &sVl[db0]);
        gload_lds16(Vl + vo1 + k0, &sVl[db1]);
        __syncthreads();
        const bf16x8 ah0 = *(const bf16x8*)&sUh[aoff[0]];
        const bf16x8 ah1 = *(const bf16x8*)&sUh[aoff[1]];
        const bf16x8 al0 = *(const bf16x8*)&sUl[aoff[0]];
        const bf16x8 al1 = *(const bf16x8*)&sUl[aoff[1]];
#pragma unroll
        for (int n = 0; n < 8; n++) {
            const bf16x8 bh = *(const bf16x8*)&sVh[boff[n]];
            const bf16x8 bl = *(const bf16x8*)&sVl[boff[n]];
            acc[0][n] = __builtin_amdgcn_mfma_f32_16x16x32_bf16(ah0, bh, acc[0][n], 0, 0, 0);
            acc[0][n] = __builtin_amdgcn_mfma_f32_16x16x32_bf16(ah0, bl, acc[0][n], 0, 0, 0);
            acc[0][n] = __builtin_amdgcn_mfma_f32_16x16x32_bf16(al0, bh, acc[0][n], 0, 0, 0);
            acc[1][n] = __builtin_amdgcn_mfma_f32_16x16x32_bf16(ah1, bh, acc[1][n], 0, 0, 0);
            acc[1][n] = __builtin_amdgcn_mfma_f32_16x16x32_bf16(ah1, bl, acc[1][n], 0, 0, 0);
            acc[1][n] = __builtin_amdgcn_mfma_f32_16x16x32_bf16(al1, bh, acc[1][n], 0, 0, 0);
        }
    }

    // per-tile stats: rows are wave-local (wave = 32 rows x 128 cols)
#pragma unroll
    for (int m = 0; m < 2; m++) {
        float mt[4] = {-__builtin_inff(), -__builtin_inff(), -__builtin_inff(), -__builtin_inff()};
#pragma unroll
        for (int n = 0; n < 8; n++) {
            const int col = col0 + n * 16 + fr;
            if (col < length) {
#pragma unroll
                for (int j = 0; j < 4; j++) mt[j] = fmaxf(mt[j], acc[m][n][j]);
            }
        }
#pragma unroll
        for (int d = 1; d < 16; d <<= 1) {
#pragma unroll
            for (int j = 0; j < 4; j++) mt[j] = fmaxf(mt[j], __shfl_xor(mt[j], d));
        }
        float rs[4] = {0.f, 0.f, 0.f, 0.f};
#pragma unroll
        for (int n = 0; n < 8; n++) {
            const int col = col0 + n * 16 + fr;
            const bool valid = (col < length);
#pragma unroll
            for (int j = 0; j < 4; j++) {
                const float p = valid ? __expf(acc[m][n][j] - mt[j]) : 0.f;
                rs[j] += p;
                const size_t row = (size_t)b * LU_ + row0 + w * 32 + m * 16 + fg * 4 + j;
                Pp[row * LV_ + col] = f2bf(p);
            }
        }
#pragma unroll
        for (int d = 1; d < 16; d <<= 1) {
#pragma unroll
            for (int j = 0; j < 4; j++) rs[j] += __shfl_xor(rs[j], d);
        }
        if (fr == 0) {
#pragma unroll
            for (int j = 0; j < 4; j++) {
                const size_t row = (size_t)b * LU_ + row0 + w * 32 + m * 16 + fg * 4 + j;
                m_used[row * NT_ + vt] = mt[j];
                Z_used[row * NT_ + vt] = rs[j];
            }
        }
    }
}

// ---------------------------------------------------------------------------
// K5: combine per-tile stats -> Sc[row][vt] = exp(m_t - m_fin) / Z
__global__ __launch_bounds__(256) void stats_combine_kernel(
    const float* __restrict__ m_used, const float* __restrict__ Z_used,
    float* __restrict__ Sc) {
    const int row = blockIdx.x * 256 + threadIdx.x;
    float mv[NT_];
    float m = -__builtin_inff();
#pragma unroll
    for (int i = 0; i < NT_; i++) {
        mv[i] = m_used[(size_t)row * NT_ + i];
        m = fmaxf(m, mv[i]);
    }
    float ev[NT_];
    float z = 0.f;
#pragma unroll
    for (int i = 0; i < NT_; i++) {
        ev[i] = __expf(mv[i] - m);
        z += Z_used[(size_t)row * NT_ + i] * ev[i];
    }
    const float inv = 1.f / z;
#pragma unroll
    for (int i = 0; i < NT_; i++) Sc[(size_t)row * NT_ + i] = ev[i] * inv;
}

// ---------------------------------------------------------------------------
// K6: out = sum_vt Sc(row,vt) * (P'_vt @ V_vt). 128x128 tile, BK=64,
// 4 waves 2x2 of 64x64, gload_lds + swizzle, scale folded per v-tile.
__global__ __launch_bounds__(256, 2) void pv_gemm_kernel(
    const unsigned short* __restrict__ Pp, const unsigned short* __restrict__ VT,
    const float* __restrict__ Sc, float* __restrict__ Out) {
    __shared__ alignas(16) unsigned short sA[128 * 64], sB[128 * 64];
    const int b = blockIdx.z, bm = blockIdx.x, bn = blockIdx.y;
    const int t = threadIdx.x, lane = t & 63, w = t >> 6;
    const int wr = (w >> 1) * 64, wc = (w & 1) * 64;
    const int fr = lane & 15, fg = lane >> 4;

    // staging: wave w rows [w*32, +32), issue i in {0..3} rows [w*32+i*8, +8)
    size_t aog[4], bog[4];
    int dbs[4];
#pragma unroll
    for (int i = 0; i < 4; i++) {
        const int r = w * 32 + i * 8 + (lane >> 3);
        const int cg = (lane & 7) ^ (r & 7);
        aog[i] = ((size_t)b * LU_ + bm * 128 + r) * LV_ + cg * 8;
        bog[i] = ((size_t)b * D_ + bn * 128 + r) * LV_ + cg * 8;
        dbs[i] = (w * 32 + i * 8) * 64;
    }
    int aoff[2][4], boff[2][4];
#pragma unroll
    for (int kk = 0; kk < 2; kk++) {
#pragma unroll
        for (int m = 0; m < 4; m++) {
            const int r = wr + m * 16 + fr;
            aoff[kk][m] = r * 64 + (((kk * 4 + fg) ^ (r & 7))) * 8;
        }
#pragma unroll
        for (int n = 0; n < 4; n++) {
            const int r = wc + n * 16 + fr;
            boff[kk][n] = r * 64 + (((kk * 4 + fg) ^ (r & 7))) * 8;
        }
    }

    const f32x4 fzero = {0.f, 0.f, 0.f, 0.f};
    f32x4 acc[4][4];
#pragma unroll
    for (int m = 0; m < 4; m++)
#pragma unroll
        for (int n = 0; n < 4; n++) acc[m][n] = fzero;

    const int rowb = bm * 128 + wr + fg * 4;   // + m*16 + j

    for (int vt = 0; vt < NT_; ++vt) {
        f32x4 part[4][4];
#pragma unroll
        for (int m = 0; m < 4; m++)
#pragma unroll
            for (int n = 0; n < 4; n++) part[m][n] = fzero;

#pragma unroll 1
        for (int kb = 0; kb < 2; ++kb) {
            const int k0 = vt * 128 + kb * 64;
            __syncthreads();
#pragma unroll
            for (int i = 0; i < 4; i++) {
                gload_lds16(Pp + aog[i] + k0, &sA[dbs[i]]);
                gload_lds16(VT + bog[i] + k0, &sB[dbs[i]]);
            }
            __syncthreads();
#pragma unroll
            for (int kk = 0; kk < 2; kk++) {
                bf16x8 af[4];
#pragma unroll
                for (int m = 0; m < 4; m++) af[m] = *(const bf16x8*)&sA[aoff[kk][m]];
#pragma unroll
                for (int n = 0; n < 4; n++) {
                    const bf16x8 bv = *(const bf16x8*)&sB[boff[kk][n]];
#pragma unroll
                    for (int m = 0; m < 4; m++)
                        part[m][n] = __builtin_amdgcn_mfma_f32_16x16x32_bf16(af[m], bv, part[m][n], 0, 0, 0);
                }
            }
        }
        float sc[4][4];
#pragma unroll
        for (int m = 0; m < 4; m++)
#pragma unroll
            for (int j = 0; j < 4; j++)
                sc[m][j] = Sc[((size_t)b * LU_ + rowb + m * 16 + j) * NT_ + vt];
#pragma unroll
        for (int m = 0; m < 4; m++)
#pragma unroll
            for (int n = 0; n < 4; n++)
#pragma unroll
                for (int j = 0; j < 4; j++)
                    acc[m][n][j] += sc[m][j] * part[m][n][j];
    }

    float* Ob = Out + (size_t)b * LU_ * D_;
#pragma unroll
    for (int m = 0; m < 4; m++) {
        const int rbase = bm * 128 + wr + m * 16 + fg * 4;
#pragma unroll
        for (int n = 0; n < 4; n++) {
            const int col = bn * 128 + wc + n * 16 + fr;
#pragma unroll
            for (int j = 0; j < 4; j++)
                Ob[(size_t)(rbase + j) * D_ + col] = acc[m][n][j];
        }
    }
}

// ---------------------------------------------------------------------------
extern "C" void kernel_launch(void* const* d_in, const int* in_sizes, int n_in,
                              void* d_out, int out_size, void* d_ws, size_t ws_size,
                              hipStream_t stream) {
    (void)in_sizes; (void)n_in; (void)out_size; (void)ws_size;
    const float* u    = (const float*)d_in[0];
    const float* v    = (const float*)d_in[1];
    const void*  vm   = d_in[2];
    const float* W    = (const float*)d_in[3];
    const float* bias = (const float*)d_in[4];
    float* out = (float*)d_out;
    char* ws = (char*)d_ws;

    // ws layout (max concurrent ~464 MB; xs region reused by Pp)
    unsigned short* xs_hi = (unsigned short*)(ws + 0 * MB_);      // 64MB (transient)
    unsigned short* xs_lo = (unsigned short*)(ws + 64 * MB_);     // 64MB (transient)
    unsigned short* Pp    = (unsigned short*)(ws + 0 * MB_);      // 128MB (aliases xs, after projs)
    unsigned short* vT    = (unsigned short*)(ws + 128 * MB_);    // 64MB
    unsigned short* W_hi  = (unsigned short*)(ws + 192 * MB_);    // 2MB
    unsigned short* W_lo  = (unsigned short*)(ws + 194 * MB_);    // 2MB
    int*   lengths = (int*)(ws + 196 * MB_);
    float* m_used  = (float*)(ws + 197 * MB_);                    // 2MB
    float* Z_used  = (float*)(ws + 199 * MB_);                    // 2MB
    float* Sc      = (float*)(ws + 201 * MB_);                    // 2MB
    unsigned short* u_hi = (unsigned short*)(ws + 208 * MB_);     // 64MB
    unsigned short* u_lo = (unsigned short*)(ws + 272 * MB_);
    unsigned short* v_hi = (unsigned short*)(ws + 336 * MB_);
    unsigned short* v_lo = (unsigned short*)(ws + 400 * MB_);     // end 464MB

    const long nW8 = (long)D_ * D_ / 8;
    const long nX8 = (long)B_ * LU_ * D_ / 8;

    lengths_kernel<<<1, 256, 0, stream>>>(vm, lengths);
    split_kernel<<<512, 256, 0, stream>>>(W, W_hi, W_lo, nW8);
    split_kernel<<<4096, 256, 0, stream>>>(u, xs_hi, xs_lo, nX8);
    proj_kernel<<<dim3(B_ * LU_ / 128, D_ / 128), 256, 0, stream>>>(
        xs_hi, xs_lo, W_hi, W_lo, bias, u_hi, u_lo);
    split_kernel<<<4096, 256, 0, stream>>>(v, xs_hi, xs_lo, nX8);
    proj_kernel<<<dim3(B_ * LV_ / 128, D_ / 128), 256, 0, stream>>>(
        xs_hi, xs_lo, W_hi, W_lo, bias, v_hi, v_lo);
    transpose_v_kernel<<<dim3(LV_ / 64, D_ / 64, B_), 256, 0, stream>>>(v, vT);
    attn_logits_kernel<<<dim3(LU_ / 128, NT_, B_), 256, 0, stream>>>(
        u_hi, u_lo, v_hi, v_lo, lengths, Pp, m_used, Z_used);
    stats_combine_kernel<<<B_ * LU_ / 256, 256, 0, stream>>>(m_used, Z_used, Sc);
    pv_gemm_kernel<<<dim3(LU_ / 128, D_ / 128, B_), 256, 0, stream>>>(Pp, vT, Sc, out);
}